// Round 1
// baseline (11.757 us; speedup 1.0000x reference)
//
#include <hip/hip_runtime.h>

// Analytic collapse of the 8-qubit circuit:
//   state after RY is a product state; CNOT ring is a basis permutation.
//   <Z_0> = prod_{q=1..7} cos(x_q);  <Z_k> = prod_{q=0..k} cos(x_q), k=1..7.
__global__ __launch_bounds__(256) void QuantumLayer_kernel(
    const float* __restrict__ x, float* __restrict__ out, int B) {
    int i = blockIdx.x * blockDim.x + threadIdx.x;
    if (i >= B) return;

    const float4* xv = reinterpret_cast<const float4*>(x) + 2 * (size_t)i;
    float4 a = xv[0];
    float4 b = xv[1];

    float c0 = cosf(a.x);
    float c1 = cosf(a.y);
    float c2 = cosf(a.z);
    float c3 = cosf(a.w);
    float c4 = cosf(b.x);
    float c5 = cosf(b.y);
    float c6 = cosf(b.z);
    float c7 = cosf(b.w);

    // prefix products p_k = c0*...*ck
    float p1 = c0 * c1;
    float p2 = p1 * c2;
    float p3 = p2 * c3;
    float p4 = p3 * c4;
    float p5 = p4 * c5;
    float p6 = p5 * c6;
    float p7 = p6 * c7;

    // out0 = c1*...*c7 (suffix, avoid division by c0)
    float s = c1 * c2;
    s = s * c3;
    s = s * c4;
    s = s * c5;
    s = s * c6;
    s = s * c7;

    float4 o0 = make_float4(s, p1, p2, p3);
    float4 o1 = make_float4(p4, p5, p6, p7);

    float4* ov = reinterpret_cast<float4*>(out) + 2 * (size_t)i;
    ov[0] = o0;
    ov[1] = o1;
}

extern "C" void kernel_launch(void* const* d_in, const int* in_sizes, int n_in,
                              void* d_out, int out_size, void* d_ws, size_t ws_size,
                              hipStream_t stream) {
    const float* x = (const float*)d_in[0];
    float* out = (float*)d_out;
    int B = in_sizes[0] / 8;  // 524288
    int block = 256;
    int grid = (B + block - 1) / block;
    QuantumLayer_kernel<<<grid, block, 0, stream>>>(x, out, B);
}

// Round 2
// 10.826 us; speedup vs baseline: 1.0860x; 1.0860x over previous
//
#include <hip/hip_runtime.h>

// Analytic collapse of the 8-qubit circuit:
//   state after RY is a product state; CNOT ring is a basis permutation.
//   <Z_0> = prod_{q=1..7} cos(x_q);  <Z_k> = prod_{q=0..k} cos(x_q), k=1..7.
// __cosf: native v_cos_f32 (input range-reduced), ~1e-4 abs error for |x|<6,
// vs 2e-2 harness threshold — 8x fewer VALU ops than libm cosf.
__global__ __launch_bounds__(256) void QuantumLayer_kernel(
    const float* __restrict__ x, float* __restrict__ out, int B) {
    int i = blockIdx.x * blockDim.x + threadIdx.x;
    if (i >= B) return;

    const float4* xv = reinterpret_cast<const float4*>(x) + 2 * (size_t)i;
    float4 a = xv[0];
    float4 b = xv[1];

    float c0 = __cosf(a.x);
    float c1 = __cosf(a.y);
    float c2 = __cosf(a.z);
    float c3 = __cosf(a.w);
    float c4 = __cosf(b.x);
    float c5 = __cosf(b.y);
    float c6 = __cosf(b.z);
    float c7 = __cosf(b.w);

    // prefix products p_k = c0*...*ck
    float p1 = c0 * c1;
    float p2 = p1 * c2;
    float p3 = p2 * c3;
    float p4 = p3 * c4;
    float p5 = p4 * c5;
    float p6 = p5 * c6;
    float p7 = p6 * c7;

    // out0 = c1*...*c7 (suffix product, avoids division by c0)
    float s = c1 * c2;
    s = s * c3;
    s = s * c4;
    s = s * c5;
    s = s * c6;
    s = s * c7;

    float4 o0 = make_float4(s, p1, p2, p3);
    float4 o1 = make_float4(p4, p5, p6, p7);

    float4* ov = reinterpret_cast<float4*>(out) + 2 * (size_t)i;
    ov[0] = o0;
    ov[1] = o1;
}

extern "C" void kernel_launch(void* const* d_in, const int* in_sizes, int n_in,
                              void* d_out, int out_size, void* d_ws, size_t ws_size,
                              hipStream_t stream) {
    const float* x = (const float*)d_in[0];
    float* out = (float*)d_out;
    int B = in_sizes[0] / 8;  // 524288
    int block = 256;
    int grid = (B + block - 1) / block;
    QuantumLayer_kernel<<<grid, block, 0, stream>>>(x, out, B);
}